// Round 11
// baseline (780.101 us; speedup 1.0000x reference)
//
#include <hip/hip_runtime.h>
#include <hip/hip_bf16.h>
#include <hip/hip_fp16.h>

#define NRANGE   8       // node ranges (LDS accumulator tiles)
#define RLEN_MAX 12800   // floats per range in LDS (51.2 KB)
#define N_XCD    8       // MI355X XCDs; blockIdx%8 ~ XCD round-robin
#define SL_XCD   4       // slices per XCD
#define SLICES   32      // total edge slices
#define WIN_E    2048    // edges per etrec block (512 thr * 4)

typedef float vfloat4 __attribute__((ext_vector_type(4)));
typedef unsigned long long u64;

// Pack (T, cp) per node into float2; also zero the 32 slice tails
// (replaces a separate memset dispatch).
__global__ void __launch_bounds__(256)
pack_nodes_kernel(const float* __restrict__ T, const float* __restrict__ cp,
                  float2* __restrict__ nodes, int* __restrict__ tails, int n) {
    int i = blockIdx.x * blockDim.x + threadIdx.x;
    if (i < n) nodes[i] = make_float2(T[i], cp[i]);
    if (blockIdx.x == 0 && threadIdx.x < SLICES) tails[threadIdx.x] = 0;
}

__device__ __forceinline__ float edge_e(float2 ns, float2 nd, float Li,
                                        float ci, float Ai, float dt) {
    const float delta = ns.x - nd.x;
    if (delta <= 0.0f) return 0.0f;
    const float x = (delta / Li) * ci;
    const float ec = cbrtf(x) * Ai * dt;
    const float comb = (nd.y * ns.y) / (nd.y + ns.y);
    return fminf(ec, delta * comb);
}

// record = s(17b) | d(17b)<<17 | f16(e)<<34  (only nonzero edges recorded)
__device__ __forceinline__ u64 make_rec(int s, int d, float e) {
    return (u64)(unsigned)s | ((u64)(unsigned)d << 17)
         | ((u64)__half_as_ushort(__float2half_rn(e)) << 34);
}

// Wave-level compaction of one edge slot: ballot -> one global atomic per
// wave -> prefix-offset coalesced store. No LDS, no barriers.
__device__ __forceinline__ void emit_rec(float e, int sv, int dv,
                                         int* __restrict__ tail,
                                         u64* __restrict__ dp, int cap) {
    const u64 mask = __ballot(e > 0.0f);
    if (mask == 0ull) return;
    const int lane = threadIdx.x & 63;
    const int leader = __ffsll((long long)mask) - 1;
    int base = 0;
    if (lane == leader) base = atomicAdd(tail, __popcll(mask));
    base = __shfl(base, leader, 64);
    if (e > 0.0f) {
        const int off = __popcll(mask & ((1ull << lane) - 1ull));
        const int p = base + off;
        if (p < cap) dp[p] = make_rec(sv, dv, e);
    }
}

// One block per 2048-edge window, XCD-swizzled so each slice's records are
// produced and later consumed through the SAME XCD's L2.
__global__ void __launch_bounds__(512)
etrec_kernel(const float2* __restrict__ nodes,
             const float* __restrict__ L,
             const float* __restrict__ cond,
             const float* __restrict__ A,
             const float* __restrict__ time_step,
             const int* __restrict__ src,
             const int* __restrict__ dst,
             u64* __restrict__ recs,      // [SLICES][cap]
             int* __restrict__ tails,     // [SLICES]
             int n_edges, int wps, int cap) {
    const int wpx = SL_XCD * wps;                         // windows per xcd
    const int w   = (blockIdx.x % N_XCD) * wpx + blockIdx.x / N_XCD;
    const int s   = w / wps;                              // slice of this window
    const int e0  = w * WIN_E;
    if (e0 >= n_edges) return;

    u64* __restrict__ dp = recs + (size_t)s * cap;
    const float dt = time_step[0];
    const int e1 = min(n_edges, e0 + WIN_E);
    const int ng = (e1 - e0) >> 2;                        // full vec4 groups
    const int g  = threadIdx.x;

    if (g < ng) {
        const int kk = (e0 >> 2) + g;                     // e0 % 4 == 0
        const int4    si = ((const int4*)src)[kk];
        const int4    di = ((const int4*)dst)[kk];
        const vfloat4 Lv = __builtin_nontemporal_load(&((const vfloat4*)L)[kk]);
        const vfloat4 cv = __builtin_nontemporal_load(&((const vfloat4*)cond)[kk]);
        const vfloat4 Av = __builtin_nontemporal_load(&((const vfloat4*)A)[kk]);
        const float2 ns0 = nodes[si.x], ns1 = nodes[si.y], ns2 = nodes[si.z], ns3 = nodes[si.w];
        const float2 nd0 = nodes[di.x], nd1 = nodes[di.y], nd2 = nodes[di.z], nd3 = nodes[di.w];
        const float ex = edge_e(ns0, nd0, Lv.x, cv.x, Av.x, dt);
        const float ey = edge_e(ns1, nd1, Lv.y, cv.y, Av.y, dt);
        const float ez = edge_e(ns2, nd2, Lv.z, cv.z, Av.z, dt);
        const float ew = edge_e(ns3, nd3, Lv.w, cv.w, Av.w, dt);
        emit_rec(ex, si.x, di.x, &tails[s], dp, cap);
        emit_rec(ey, si.y, di.y, &tails[s], dp, cap);
        emit_rec(ez, si.z, di.z, &tails[s], dp, cap);
        emit_rec(ew, si.w, di.w, &tails[s], dp, cap);
    } else {
        // keep whole waves converged for ballot correctness in the main path;
        // tail edges (n_edges % 4) handled per-lane here
        const int tb = e0 + (ng << 2);
        const int ti = tb + (g - ng);
        if (ti < e1) {
            const float e = edge_e(nodes[src[ti]], nodes[dst[ti]], L[ti], cond[ti], A[ti], dt);
            if (e > 0.0f) {
                const int p = atomicAdd(&tails[s], 1);
                if (p < cap) dp[p] = make_rec(src[ti], dst[ti], e);
            }
        }
    }
}

// Block (r,b) XCD-swizzled; scans slice b's compacted records (8B/nonzero
// edge, XCD-L2-resident across the 8 range re-reads).
__global__ void __launch_bounds__(512)
accrec_kernel(const u64* __restrict__ recs,
              const int* __restrict__ tails,
              float* __restrict__ copies,   // [SLICES][n_nodes]
              int n_nodes, int R, int cap) {
    __shared__ float lds[RLEN_MAX];
    const int xcd = blockIdx.x % N_XCD;
    const int j   = blockIdx.x / N_XCD;
    const int r   = j % NRANGE;
    const int b   = xcd * SL_XCD + j / NRANGE;
    const int base = r * R;
    const int rlen = min(R, n_nodes - base);

    for (int t = threadIdx.x; t < rlen; t += 512) lds[t] = 0.0f;
    __syncthreads();

    const int cnt = min(tails[b], cap);
    const u64* __restrict__ g = recs + (size_t)b * cap;
    for (int t = threadIdx.x; t < cnt; t += 512) {
        const u64 rec = g[t];
        const int   sv = (int)(rec & 0x1FFFF);
        const int   dv = (int)((rec >> 17) & 0x1FFFF);
        const float e  = __half2float(__ushort_as_half((unsigned short)(rec >> 34)));
        const int ls = sv - base; if ((unsigned)ls < (unsigned)rlen) atomicAdd(&lds[ls], -e);
        const int ld = dv - base; if ((unsigned)ld < (unsigned)rlen) atomicAdd(&lds[ld],  e);
    }
    __syncthreads();

    // Exclusive region of copies[b]: plain coalesced stores (covers all rlen).
    float* __restrict__ cpy = copies + (size_t)b * n_nodes + base;
    for (int t = threadIdx.x; t < rlen; t += 512) cpy[t] = lds[t];
}

// out[i..i+3] = sum over the 32 slices, float4-vectorized.
__global__ void __launch_bounds__(256)
reduce_copies_kernel(const float* __restrict__ copies, float* __restrict__ out,
                     int n_nodes) {
    const int k = blockIdx.x * blockDim.x + threadIdx.x;
    const int nvec = n_nodes >> 2;
    if (k < nvec) {
        vfloat4 v = {0.f, 0.f, 0.f, 0.f};
        for (int b = 0; b < SLICES; ++b)
            v += ((const vfloat4*)(copies + (size_t)b * n_nodes))[k];
        ((vfloat4*)out)[k] = v;
    } else if (k == nvec) {
        for (int i = nvec << 2; i < n_nodes; ++i) {
            float v = 0.0f;
            for (int b = 0; b < SLICES; ++b) v += copies[(size_t)b * n_nodes + i];
            out[i] = v;
        }
    }
}

// Fallback (shape/ws mismatch): direct device-scope atomics into d_out.
__global__ void __launch_bounds__(256)
conduction_edge_direct(const float* __restrict__ T, const float* __restrict__ cp,
                       const float* __restrict__ L, const float* __restrict__ cond,
                       const float* __restrict__ A, const float* __restrict__ time_step,
                       const int* __restrict__ src, const int* __restrict__ dst,
                       float* __restrict__ out, int n_edges) {
    int i = blockIdx.x * blockDim.x + threadIdx.x;
    if (i >= n_edges) return;
    const int s = src[i], d = dst[i];
    float delta = T[s] - T[d];
    if (delta <= 0.0f) return;
    const float dt = time_step[0];
    const float x = (delta / L[i]) * cond[i];
    const float e_cond = cbrtf(x) * A[i] * dt;
    const float cs = cp[s], cd = cp[d];
    const float max_e = delta * (cd * cs) / (cd + cs);
    const float Et = fminf(e_cond, max_e);
    atomicAdd(&out[d],  Et);
    atomicAdd(&out[s], -Et);
}

extern "C" void kernel_launch(void* const* d_in, const int* in_sizes, int n_in,
                              void* d_out, int out_size, void* d_ws, size_t ws_size,
                              hipStream_t stream) {
    const float* T    = (const float*)d_in[0];
    const float* cp   = (const float*)d_in[1];
    const float* L    = (const float*)d_in[2];
    const float* cond = (const float*)d_in[3];
    const float* A    = (const float*)d_in[4];
    const float* ts   = (const float*)d_in[5];
    const int*   src  = (const int*)d_in[6];
    const int*   dst  = (const int*)d_in[7];
    float* out = (float*)d_out;

    const int n_nodes = in_sizes[0];
    const int n_edges = in_sizes[2];

    const int block = 256;
    const int ngrid = (n_nodes + block - 1) / block;
    const int R = (n_nodes + NRANGE - 1) / NRANGE;

    // chunk (edges/slice): multiple of WIN_E so windows never straddle slices
    int chunk = (n_edges + SLICES - 1) / SLICES;
    chunk = (chunk + WIN_E - 1) & ~(WIN_E - 1);
    const int wps = chunk / WIN_E;                 // windows per slice
    const int cap = (chunk >> 3) * 5;              // 62.5% of chunk (~+100 sigma)

    const size_t tails_bytes = 256;                                // 32*4, padded
    const size_t nodes_bytes = (size_t)n_nodes * sizeof(float2);
    const size_t recs_bytes  = (size_t)SLICES * cap * sizeof(u64);
    const size_t copy_bytes  = (size_t)SLICES * n_nodes * sizeof(float);
    const size_t need = tails_bytes + nodes_bytes + recs_bytes + copy_bytes;

    if (R <= RLEN_MAX && n_nodes <= (1 << 17) && ws_size >= need) {
        int*    tails  = (int*)d_ws;
        float2* nodes  = (float2*)((char*)d_ws + tails_bytes);
        u64*    recs   = (u64*)((char*)d_ws + tails_bytes + nodes_bytes);
        float*  copies = (float*)((char*)d_ws + tails_bytes + nodes_bytes + recs_bytes);

        pack_nodes_kernel<<<ngrid, block, 0, stream>>>(T, cp, nodes, tails, n_nodes);
        etrec_kernel<<<SLICES * wps, 512, 0, stream>>>(
            nodes, L, cond, A, ts, src, dst, recs, tails, n_edges, wps, cap);
        accrec_kernel<<<N_XCD * SL_XCD * NRANGE, 512, 0, stream>>>(
            recs, tails, copies, n_nodes, R, cap);
        const int rgrid = ((n_nodes >> 2) + 1 + block - 1) / block;
        reduce_copies_kernel<<<rgrid, block, 0, stream>>>(copies, out, n_nodes);
    } else {
        (void)hipMemsetAsync(out, 0, (size_t)out_size * sizeof(float), stream);
        const int egrid = (n_edges + block - 1) / block;
        conduction_edge_direct<<<egrid, block, 0, stream>>>(
            T, cp, L, cond, A, ts, src, dst, out, n_edges);
    }
}

// Round 12
// 270.581 us; speedup vs baseline: 2.8831x; 2.8831x over previous
//
#include <hip/hip_runtime.h>
#include <hip/hip_bf16.h>
#include <hip/hip_fp16.h>

#define NRANGE   8       // node ranges (LDS accumulator tiles)
#define RLEN_MAX 12800   // floats per range in LDS (51.2 KB)
#define N_XCD    8       // MI355X XCDs; blockIdx%8 ~ XCD round-robin
#define SL_XCD   4       // slices per XCD
#define SLICES   32      // total edge slices
#define WIN_E    2048    // edges per etrec block (512 thr * 4)

typedef float vfloat4 __attribute__((ext_vector_type(4)));
typedef unsigned long long u64;

// Pack (T, cp) per node into float2; also zero the 32 slice tails
// (replaces a separate memset dispatch).
__global__ void __launch_bounds__(256)
pack_nodes_kernel(const float* __restrict__ T, const float* __restrict__ cp,
                  float2* __restrict__ nodes, int* __restrict__ tails, int n) {
    int i = blockIdx.x * blockDim.x + threadIdx.x;
    if (i < n) nodes[i] = make_float2(T[i], cp[i]);
    if (blockIdx.x == 0 && threadIdx.x < SLICES) tails[threadIdx.x] = 0;
}

__device__ __forceinline__ float edge_e(float2 ns, float2 nd, float Li,
                                        float ci, float Ai, float dt) {
    const float delta = ns.x - nd.x;
    if (delta <= 0.0f) return 0.0f;
    const float x = (delta / Li) * ci;
    const float ec = cbrtf(x) * Ai * dt;
    const float comb = (nd.y * ns.y) / (nd.y + ns.y);
    return fminf(ec, delta * comb);
}

// record = s(17b) | d(17b)<<17 | f16(e)<<34  (only nonzero edges recorded)
__device__ __forceinline__ u64 make_rec(int s, int d, float e) {
    return (u64)(unsigned)s | ((u64)(unsigned)d << 17)
         | ((u64)__half_as_ushort(__float2half_rn(e)) << 34);
}

// One block per 2048-edge window, XCD-swizzled so each slice's records are
// produced and consumed through the SAME XCD's L2.
// Compaction: per-wave ballot + register running offset into a private LDS
// segment (ZERO atomics), then ONE global atomicAdd per block (latency
// hidden behind the barrier — the R11 per-wave device atomic was a 7x
// regression; the R10 per-element LDS atomic cost ~2K serialized cyc/block).
__global__ void __launch_bounds__(512)
etrec_kernel(const float2* __restrict__ nodes,
             const float* __restrict__ L,
             const float* __restrict__ cond,
             const float* __restrict__ A,
             const float* __restrict__ time_step,
             const int* __restrict__ src,
             const int* __restrict__ dst,
             u64* __restrict__ recs,      // [SLICES][cap]
             int* __restrict__ tails,     // [SLICES]
             int n_edges, int wps, int cap) {
    __shared__ u64 srec[8 * 256];        // 8 waves x 256 records, 16 KB
    __shared__ int wcnt[8];
    __shared__ int wbase[8];
    __shared__ int sbase;

    const int wpx  = SL_XCD * wps;                        // windows per xcd
    const int w    = (blockIdx.x % N_XCD) * wpx + blockIdx.x / N_XCD;
    const int s    = w / wps;                             // slice of this window
    const int e0   = w * WIN_E;
    const int wave = threadIdx.x >> 6;
    const int lane = threadIdx.x & 63;

    int my_off = 0;                                       // wave-local count
    const bool active = (e0 < n_edges);

    if (active) {
        const float dt = time_step[0];
        float ev[4]; int sv[4]; int dv[4];

        if (e0 + WIN_E <= n_edges) {                      // full window: vec4
            const int kk = (e0 >> 2) + threadIdx.x;       // e0 % 4 == 0
            const int4    si = ((const int4*)src)[kk];
            const int4    di = ((const int4*)dst)[kk];
            const vfloat4 Lv = __builtin_nontemporal_load(&((const vfloat4*)L)[kk]);
            const vfloat4 cv = __builtin_nontemporal_load(&((const vfloat4*)cond)[kk]);
            const vfloat4 Av = __builtin_nontemporal_load(&((const vfloat4*)A)[kk]);
            const float2 ns0 = nodes[si.x], ns1 = nodes[si.y], ns2 = nodes[si.z], ns3 = nodes[si.w];
            const float2 nd0 = nodes[di.x], nd1 = nodes[di.y], nd2 = nodes[di.z], nd3 = nodes[di.w];
            ev[0] = edge_e(ns0, nd0, Lv.x, cv.x, Av.x, dt);
            ev[1] = edge_e(ns1, nd1, Lv.y, cv.y, Av.y, dt);
            ev[2] = edge_e(ns2, nd2, Lv.z, cv.z, Av.z, dt);
            ev[3] = edge_e(ns3, nd3, Lv.w, cv.w, Av.w, dt);
            sv[0] = si.x; sv[1] = si.y; sv[2] = si.z; sv[3] = si.w;
            dv[0] = di.x; dv[1] = di.y; dv[2] = di.z; dv[3] = di.w;
        } else {                                          // partial last window
#pragma unroll
            for (int j = 0; j < 4; ++j) {
                const int i = e0 + 4 * (int)threadIdx.x + j;
                float e = 0.0f; int a = 0, b2 = 0;
                if (i < n_edges) {
                    a = src[i]; b2 = dst[i];
                    e = edge_e(nodes[a], nodes[b2], L[i], cond[i], A[i], dt);
                }
                ev[j] = e; sv[j] = a; dv[j] = b2;
            }
        }

        // 4 ballot slots; running offset in register, no atomics at all.
#pragma unroll
        for (int j = 0; j < 4; ++j) {
            const u64 mask = __ballot(ev[j] > 0.0f);
            if (ev[j] > 0.0f) {
                const int pos = my_off + __popcll(mask & ((1ull << lane) - 1ull));
                srec[(wave << 8) + pos] = make_rec(sv[j], dv[j], ev[j]);
            }
            my_off += (int)__popcll(mask);
        }
    }

    if (lane == 0) wcnt[wave] = my_off;
    __syncthreads();
    if (threadIdx.x == 0) {
        int tot = 0;
#pragma unroll
        for (int i = 0; i < 8; ++i) { wbase[i] = tot; tot += wcnt[i]; }
        sbase = (tot > 0) ? atomicAdd(&tails[s], tot) : 0;  // ONE atomic/block
    }
    __syncthreads();

    if (active) {
        const int c  = wcnt[wave];
        const int gb = sbase + wbase[wave];
        u64* __restrict__ dp = recs + (size_t)s * cap;
        for (int t = lane; t < c; t += 64) {
            const int p = gb + t;
            if (p < cap) dp[p] = srec[(wave << 8) + t];
        }
    }
}

// Block (r,b) XCD-swizzled; scans slice b's compacted records (8B/nonzero
// edge, XCD-L2-resident across the 8 range re-reads).
__global__ void __launch_bounds__(512)
accrec_kernel(const u64* __restrict__ recs,
              const int* __restrict__ tails,
              float* __restrict__ copies,   // [SLICES][n_nodes]
              int n_nodes, int R, int cap) {
    __shared__ float lds[RLEN_MAX];
    const int xcd = blockIdx.x % N_XCD;
    const int j   = blockIdx.x / N_XCD;
    const int r   = j % NRANGE;
    const int b   = xcd * SL_XCD + j / NRANGE;
    const int base = r * R;
    const int rlen = min(R, n_nodes - base);

    for (int t = threadIdx.x; t < rlen; t += 512) lds[t] = 0.0f;
    __syncthreads();

    const int cnt = min(tails[b], cap);
    const u64* __restrict__ g = recs + (size_t)b * cap;
    for (int t = threadIdx.x; t < cnt; t += 512) {
        const u64 rec = g[t];
        const int   sv = (int)(rec & 0x1FFFF);
        const int   dv = (int)((rec >> 17) & 0x1FFFF);
        const float e  = __half2float(__ushort_as_half((unsigned short)(rec >> 34)));
        const int ls = sv - base; if ((unsigned)ls < (unsigned)rlen) atomicAdd(&lds[ls], -e);
        const int ld = dv - base; if ((unsigned)ld < (unsigned)rlen) atomicAdd(&lds[ld],  e);
    }
    __syncthreads();

    // Exclusive region of copies[b]: plain coalesced stores (covers all rlen).
    float* __restrict__ cpy = copies + (size_t)b * n_nodes + base;
    for (int t = threadIdx.x; t < rlen; t += 512) cpy[t] = lds[t];
}

// out[i..i+3] = sum over the 32 slices, float4-vectorized.
__global__ void __launch_bounds__(256)
reduce_copies_kernel(const float* __restrict__ copies, float* __restrict__ out,
                     int n_nodes) {
    const int k = blockIdx.x * blockDim.x + threadIdx.x;
    const int nvec = n_nodes >> 2;
    if (k < nvec) {
        vfloat4 v = {0.f, 0.f, 0.f, 0.f};
        for (int b = 0; b < SLICES; ++b)
            v += ((const vfloat4*)(copies + (size_t)b * n_nodes))[k];
        ((vfloat4*)out)[k] = v;
    } else if (k == nvec) {
        for (int i = nvec << 2; i < n_nodes; ++i) {
            float v = 0.0f;
            for (int b = 0; b < SLICES; ++b) v += copies[(size_t)b * n_nodes + i];
            out[i] = v;
        }
    }
}

// Fallback (shape/ws mismatch): direct device-scope atomics into d_out.
__global__ void __launch_bounds__(256)
conduction_edge_direct(const float* __restrict__ T, const float* __restrict__ cp,
                       const float* __restrict__ L, const float* __restrict__ cond,
                       const float* __restrict__ A, const float* __restrict__ time_step,
                       const int* __restrict__ src, const int* __restrict__ dst,
                       float* __restrict__ out, int n_edges) {
    int i = blockIdx.x * blockDim.x + threadIdx.x;
    if (i >= n_edges) return;
    const int s = src[i], d = dst[i];
    float delta = T[s] - T[d];
    if (delta <= 0.0f) return;
    const float dt = time_step[0];
    const float x = (delta / L[i]) * cond[i];
    const float e_cond = cbrtf(x) * A[i] * dt;
    const float cs = cp[s], cd = cp[d];
    const float max_e = delta * (cd * cs) / (cd + cs);
    const float Et = fminf(e_cond, max_e);
    atomicAdd(&out[d],  Et);
    atomicAdd(&out[s], -Et);
}

extern "C" void kernel_launch(void* const* d_in, const int* in_sizes, int n_in,
                              void* d_out, int out_size, void* d_ws, size_t ws_size,
                              hipStream_t stream) {
    const float* T    = (const float*)d_in[0];
    const float* cp   = (const float*)d_in[1];
    const float* L    = (const float*)d_in[2];
    const float* cond = (const float*)d_in[3];
    const float* A    = (const float*)d_in[4];
    const float* ts   = (const float*)d_in[5];
    const int*   src  = (const int*)d_in[6];
    const int*   dst  = (const int*)d_in[7];
    float* out = (float*)d_out;

    const int n_nodes = in_sizes[0];
    const int n_edges = in_sizes[2];

    const int block = 256;
    const int ngrid = (n_nodes + block - 1) / block;
    const int R = (n_nodes + NRANGE - 1) / NRANGE;

    // chunk (edges/slice): multiple of WIN_E so windows never straddle slices
    int chunk = (n_edges + SLICES - 1) / SLICES;
    chunk = (chunk + WIN_E - 1) & ~(WIN_E - 1);
    const int wps = chunk / WIN_E;                 // windows per slice
    const int cap = (chunk >> 3) * 5;              // 62.5% of chunk (~+100 sigma)

    const size_t tails_bytes = 256;                                // 32*4, padded
    const size_t nodes_bytes = (size_t)n_nodes * sizeof(float2);
    const size_t recs_bytes  = (size_t)SLICES * cap * sizeof(u64);
    const size_t copy_bytes  = (size_t)SLICES * n_nodes * sizeof(float);
    const size_t need = tails_bytes + nodes_bytes + recs_bytes + copy_bytes;

    if (R <= RLEN_MAX && n_nodes <= (1 << 17) && ws_size >= need) {
        int*    tails  = (int*)d_ws;
        float2* nodes  = (float2*)((char*)d_ws + tails_bytes);
        u64*    recs   = (u64*)((char*)d_ws + tails_bytes + nodes_bytes);
        float*  copies = (float*)((char*)d_ws + tails_bytes + nodes_bytes + recs_bytes);

        pack_nodes_kernel<<<ngrid, block, 0, stream>>>(T, cp, nodes, tails, n_nodes);
        etrec_kernel<<<SLICES * wps, 512, 0, stream>>>(
            nodes, L, cond, A, ts, src, dst, recs, tails, n_edges, wps, cap);
        accrec_kernel<<<N_XCD * SL_XCD * NRANGE, 512, 0, stream>>>(
            recs, tails, copies, n_nodes, R, cap);
        const int rgrid = ((n_nodes >> 2) + 1 + block - 1) / block;
        reduce_copies_kernel<<<rgrid, block, 0, stream>>>(copies, out, n_nodes);
    } else {
        (void)hipMemsetAsync(out, 0, (size_t)out_size * sizeof(float), stream);
        const int egrid = (n_edges + block - 1) / block;
        conduction_edge_direct<<<egrid, block, 0, stream>>>(
            T, cp, L, cond, A, ts, src, dst, out, n_edges);
    }
}

// Round 13
// 248.848 us; speedup vs baseline: 3.1348x; 1.0873x over previous
//
#include <hip/hip_runtime.h>
#include <hip/hip_bf16.h>
#include <hip/hip_fp16.h>

#define NRANGE   8       // node ranges (LDS accumulator tiles)
#define RLEN_MAX 12800   // floats per range in LDS (51.2 KB)
#define N_XCD    8       // MI355X XCDs; blockIdx%8 ~ XCD round-robin
#define SL_XCD   8       // slices per XCD
#define SLICES   64      // total edge slices (64 -> 512 accrec blocks = 2/CU)
#define WIN_E    2048    // edges per etrec block (512 thr * 4)

typedef float vfloat4 __attribute__((ext_vector_type(4)));
typedef unsigned long long u64;

// Pack (T, cp) per node into float2; also zero the slice tails
// (replaces a separate memset dispatch).
__global__ void __launch_bounds__(256)
pack_nodes_kernel(const float* __restrict__ T, const float* __restrict__ cp,
                  float2* __restrict__ nodes, int* __restrict__ tails, int n) {
    int i = blockIdx.x * blockDim.x + threadIdx.x;
    if (i < n) nodes[i] = make_float2(T[i], cp[i]);
    if (blockIdx.x == 0 && threadIdx.x < SLICES) tails[threadIdx.x] = 0;
}

__device__ __forceinline__ float edge_e(float2 ns, float2 nd, float Li,
                                        float ci, float Ai, float dt) {
    const float delta = ns.x - nd.x;
    if (delta <= 0.0f) return 0.0f;
    const float x = (delta / Li) * ci;
    const float ec = cbrtf(x) * Ai * dt;
    const float comb = (nd.y * ns.y) / (nd.y + ns.y);
    return fminf(ec, delta * comb);
}

// record = s(17b) | d(17b)<<17 | f16(e)<<34  (only nonzero edges recorded)
__device__ __forceinline__ u64 make_rec(int s, int d, float e) {
    return (u64)(unsigned)s | ((u64)(unsigned)d << 17)
         | ((u64)__half_as_ushort(__float2half_rn(e)) << 34);
}

// One block per 2048-edge window, XCD-swizzled so each slice's records are
// produced and consumed through the SAME XCD's L2.
// Compaction: per-wave ballot + register running offset into a private LDS
// segment (zero per-element atomics), then ONE global atomicAdd per block.
// (R11's per-wave device atomic: 7x regression. R10's per-element LDS
// atomic: ~2K serialized cyc/block. This version: neither.)
__global__ void __launch_bounds__(512)
etrec_kernel(const float2* __restrict__ nodes,
             const float* __restrict__ L,
             const float* __restrict__ cond,
             const float* __restrict__ A,
             const float* __restrict__ time_step,
             const int* __restrict__ src,
             const int* __restrict__ dst,
             u64* __restrict__ recs,      // [SLICES][cap]
             int* __restrict__ tails,     // [SLICES]
             int n_edges, int wps, int cap) {
    __shared__ u64 srec[8 * 256];        // 8 waves x 256 records, 16 KB
    __shared__ int wcnt[8];
    __shared__ int wbase[8];
    __shared__ int sbase;

    const int wpx  = SL_XCD * wps;                        // windows per xcd
    const int w    = (blockIdx.x % N_XCD) * wpx + blockIdx.x / N_XCD;
    const int s    = w / wps;                             // slice of this window
    const int e0   = w * WIN_E;
    const int wave = threadIdx.x >> 6;
    const int lane = threadIdx.x & 63;

    int my_off = 0;                                       // wave-local count
    const bool active = (e0 < n_edges);

    if (active) {
        const float dt = time_step[0];
        float ev[4]; int sv[4]; int dv[4];

        if (e0 + WIN_E <= n_edges) {                      // full window: vec4
            const int kk = (e0 >> 2) + threadIdx.x;       // e0 % 4 == 0
            const int4    si = ((const int4*)src)[kk];
            const int4    di = ((const int4*)dst)[kk];
            const vfloat4 Lv = __builtin_nontemporal_load(&((const vfloat4*)L)[kk]);
            const vfloat4 cv = __builtin_nontemporal_load(&((const vfloat4*)cond)[kk]);
            const vfloat4 Av = __builtin_nontemporal_load(&((const vfloat4*)A)[kk]);
            const float2 ns0 = nodes[si.x], ns1 = nodes[si.y], ns2 = nodes[si.z], ns3 = nodes[si.w];
            const float2 nd0 = nodes[di.x], nd1 = nodes[di.y], nd2 = nodes[di.z], nd3 = nodes[di.w];
            ev[0] = edge_e(ns0, nd0, Lv.x, cv.x, Av.x, dt);
            ev[1] = edge_e(ns1, nd1, Lv.y, cv.y, Av.y, dt);
            ev[2] = edge_e(ns2, nd2, Lv.z, cv.z, Av.z, dt);
            ev[3] = edge_e(ns3, nd3, Lv.w, cv.w, Av.w, dt);
            sv[0] = si.x; sv[1] = si.y; sv[2] = si.z; sv[3] = si.w;
            dv[0] = di.x; dv[1] = di.y; dv[2] = di.z; dv[3] = di.w;
        } else {                                          // partial last window
#pragma unroll
            for (int j = 0; j < 4; ++j) {
                const int i = e0 + 4 * (int)threadIdx.x + j;
                float e = 0.0f; int a = 0, b2 = 0;
                if (i < n_edges) {
                    a = src[i]; b2 = dst[i];
                    e = edge_e(nodes[a], nodes[b2], L[i], cond[i], A[i], dt);
                }
                ev[j] = e; sv[j] = a; dv[j] = b2;
            }
        }

        // 4 ballot slots; running offset in register, no atomics at all.
#pragma unroll
        for (int j = 0; j < 4; ++j) {
            const u64 mask = __ballot(ev[j] > 0.0f);
            if (ev[j] > 0.0f) {
                const int pos = my_off + __popcll(mask & ((1ull << lane) - 1ull));
                srec[(wave << 8) + pos] = make_rec(sv[j], dv[j], ev[j]);
            }
            my_off += (int)__popcll(mask);
        }
    }

    if (lane == 0) wcnt[wave] = my_off;
    __syncthreads();
    if (threadIdx.x == 0) {
        int tot = 0;
#pragma unroll
        for (int i = 0; i < 8; ++i) { wbase[i] = tot; tot += wcnt[i]; }
        sbase = (tot > 0) ? atomicAdd(&tails[s], tot) : 0;  // ONE atomic/block
    }
    __syncthreads();

    if (active) {
        const int c  = wcnt[wave];
        const int gb = sbase + wbase[wave];
        u64* __restrict__ dp = recs + (size_t)s * cap;
        for (int t = lane; t < c; t += 64) {
            const int p = gb + t;
            if (p < cap) dp[p] = srec[(wave << 8) + t];
        }
    }
}

// Block (r,b) XCD-swizzled; scans slice b's compacted records (8B/nonzero
// edge, XCD-L2-resident across the 8 range re-reads). Scan vectorized:
// 2 records per 16B load, independent iterations (latency-bound otherwise).
__global__ void __launch_bounds__(512)
accrec_kernel(const u64* __restrict__ recs,
              const int* __restrict__ tails,
              float* __restrict__ copies,   // [SLICES][n_nodes]
              int n_nodes, int R, int cap) {
    __shared__ float lds[RLEN_MAX];
    const int xcd = blockIdx.x % N_XCD;
    const int j   = blockIdx.x / N_XCD;
    const int r   = j % NRANGE;
    const int b   = xcd * SL_XCD + j / NRANGE;
    const int base = r * R;
    const int rlen = min(R, n_nodes - base);

    for (int t = threadIdx.x; t < rlen; t += 512) lds[t] = 0.0f;
    __syncthreads();

    const int cnt = min(tails[b], cap);
    const u64* __restrict__ g = recs + (size_t)b * cap;   // cap*8B: 16B-aligned
    const int npair = cnt >> 1;
    const ulonglong2* __restrict__ g2 = (const ulonglong2*)g;
    for (int t = threadIdx.x; t < npair; t += 512) {
        const ulonglong2 rr = g2[t];
        {
            const u64 rec = rr.x;
            const int   sv = (int)(rec & 0x1FFFF);
            const int   dv = (int)((rec >> 17) & 0x1FFFF);
            const float e  = __half2float(__ushort_as_half((unsigned short)(rec >> 34)));
            const int ls = sv - base; if ((unsigned)ls < (unsigned)rlen) atomicAdd(&lds[ls], -e);
            const int ld = dv - base; if ((unsigned)ld < (unsigned)rlen) atomicAdd(&lds[ld],  e);
        }
        {
            const u64 rec = rr.y;
            const int   sv = (int)(rec & 0x1FFFF);
            const int   dv = (int)((rec >> 17) & 0x1FFFF);
            const float e  = __half2float(__ushort_as_half((unsigned short)(rec >> 34)));
            const int ls = sv - base; if ((unsigned)ls < (unsigned)rlen) atomicAdd(&lds[ls], -e);
            const int ld = dv - base; if ((unsigned)ld < (unsigned)rlen) atomicAdd(&lds[ld],  e);
        }
    }
    // odd tail record
    for (int t = (npair << 1) + (int)threadIdx.x; t < cnt; t += 512) {
        const u64 rec = g[t];
        const int   sv = (int)(rec & 0x1FFFF);
        const int   dv = (int)((rec >> 17) & 0x1FFFF);
        const float e  = __half2float(__ushort_as_half((unsigned short)(rec >> 34)));
        const int ls = sv - base; if ((unsigned)ls < (unsigned)rlen) atomicAdd(&lds[ls], -e);
        const int ld = dv - base; if ((unsigned)ld < (unsigned)rlen) atomicAdd(&lds[ld],  e);
    }
    __syncthreads();

    // Exclusive region of copies[b]: plain coalesced stores (covers all rlen).
    float* __restrict__ cpy = copies + (size_t)b * n_nodes + base;
    for (int t = threadIdx.x; t < rlen; t += 512) cpy[t] = lds[t];
}

// out[i..i+3] = sum over the slices, float4-vectorized.
__global__ void __launch_bounds__(256)
reduce_copies_kernel(const float* __restrict__ copies, float* __restrict__ out,
                     int n_nodes) {
    const int k = blockIdx.x * blockDim.x + threadIdx.x;
    const int nvec = n_nodes >> 2;
    if (k < nvec) {
        vfloat4 v = {0.f, 0.f, 0.f, 0.f};
        for (int b = 0; b < SLICES; ++b)
            v += ((const vfloat4*)(copies + (size_t)b * n_nodes))[k];
        ((vfloat4*)out)[k] = v;
    } else if (k == nvec) {
        for (int i = nvec << 2; i < n_nodes; ++i) {
            float v = 0.0f;
            for (int b = 0; b < SLICES; ++b) v += copies[(size_t)b * n_nodes + i];
            out[i] = v;
        }
    }
}

// Fallback (shape/ws mismatch): direct device-scope atomics into d_out.
__global__ void __launch_bounds__(256)
conduction_edge_direct(const float* __restrict__ T, const float* __restrict__ cp,
                       const float* __restrict__ L, const float* __restrict__ cond,
                       const float* __restrict__ A, const float* __restrict__ time_step,
                       const int* __restrict__ src, const int* __restrict__ dst,
                       float* __restrict__ out, int n_edges) {
    int i = blockIdx.x * blockDim.x + threadIdx.x;
    if (i >= n_edges) return;
    const int s = src[i], d = dst[i];
    float delta = T[s] - T[d];
    if (delta <= 0.0f) return;
    const float dt = time_step[0];
    const float x = (delta / L[i]) * cond[i];
    const float e_cond = cbrtf(x) * A[i] * dt;
    const float cs = cp[s], cd = cp[d];
    const float max_e = delta * (cd * cs) / (cd + cs);
    const float Et = fminf(e_cond, max_e);
    atomicAdd(&out[d],  Et);
    atomicAdd(&out[s], -Et);
}

extern "C" void kernel_launch(void* const* d_in, const int* in_sizes, int n_in,
                              void* d_out, int out_size, void* d_ws, size_t ws_size,
                              hipStream_t stream) {
    const float* T    = (const float*)d_in[0];
    const float* cp   = (const float*)d_in[1];
    const float* L    = (const float*)d_in[2];
    const float* cond = (const float*)d_in[3];
    const float* A    = (const float*)d_in[4];
    const float* ts   = (const float*)d_in[5];
    const int*   src  = (const int*)d_in[6];
    const int*   dst  = (const int*)d_in[7];
    float* out = (float*)d_out;

    const int n_nodes = in_sizes[0];
    const int n_edges = in_sizes[2];

    const int block = 256;
    const int ngrid = (n_nodes + block - 1) / block;
    const int R = (n_nodes + NRANGE - 1) / NRANGE;

    // chunk (edges/slice): multiple of WIN_E so windows never straddle slices
    int chunk = (n_edges + SLICES - 1) / SLICES;
    chunk = (chunk + WIN_E - 1) & ~(WIN_E - 1);
    const int wps = chunk / WIN_E;                 // windows per slice
    const int cap = (chunk >> 3) * 5;              // 62.5% of chunk (~+80 sigma)

    const size_t tails_bytes = 256;                                // 64*4
    const size_t nodes_bytes = (size_t)n_nodes * sizeof(float2);
    const size_t recs_bytes  = (size_t)SLICES * cap * sizeof(u64);
    const size_t copy_bytes  = (size_t)SLICES * n_nodes * sizeof(float);
    const size_t need = tails_bytes + nodes_bytes + recs_bytes + copy_bytes;

    if (R <= RLEN_MAX && n_nodes <= (1 << 17) && ws_size >= need) {
        int*    tails  = (int*)d_ws;
        float2* nodes  = (float2*)((char*)d_ws + tails_bytes);
        u64*    recs   = (u64*)((char*)d_ws + tails_bytes + nodes_bytes);
        float*  copies = (float*)((char*)d_ws + tails_bytes + nodes_bytes + recs_bytes);

        pack_nodes_kernel<<<ngrid, block, 0, stream>>>(T, cp, nodes, tails, n_nodes);
        etrec_kernel<<<SLICES * wps, 512, 0, stream>>>(
            nodes, L, cond, A, ts, src, dst, recs, tails, n_edges, wps, cap);
        accrec_kernel<<<N_XCD * SL_XCD * NRANGE, 512, 0, stream>>>(
            recs, tails, copies, n_nodes, R, cap);
        const int rgrid = ((n_nodes >> 2) + 1 + block - 1) / block;
        reduce_copies_kernel<<<rgrid, block, 0, stream>>>(copies, out, n_nodes);
    } else {
        (void)hipMemsetAsync(out, 0, (size_t)out_size * sizeof(float), stream);
        const int egrid = (n_edges + block - 1) / block;
        conduction_edge_direct<<<egrid, block, 0, stream>>>(
            T, cp, L, cond, A, ts, src, dst, out, n_edges);
    }
}

// Round 14
// 244.746 us; speedup vs baseline: 3.1874x; 1.0168x over previous
//
#include <hip/hip_runtime.h>
#include <hip/hip_bf16.h>
#include <hip/hip_fp16.h>

#define NRANGE   8       // node ranges (LDS accumulator tiles)
#define RLEN_MAX 12800   // floats per range in LDS (51.2 KB)
#define N_XCD    8       // MI355X XCDs; blockIdx%8 ~ XCD round-robin
#define SL_XCD   8       // slices per XCD
#define SLICES   64      // total edge slices (512 accrec blocks = 2/CU)
#define WIN_E    2048    // edges per etrec block (512 thr * 4)

typedef float vfloat4 __attribute__((ext_vector_type(4)));
typedef unsigned long long u64;

// Pack (T, cp) per node into float2; also zero the slice tails.
__global__ void __launch_bounds__(256)
pack_nodes_kernel(const float* __restrict__ T, const float* __restrict__ cp,
                  float2* __restrict__ nodes, int* __restrict__ tails, int n) {
    int i = blockIdx.x * blockDim.x + threadIdx.x;
    if (i < n) nodes[i] = make_float2(T[i], cp[i]);
    if (blockIdx.x == 0 && threadIdx.x < SLICES) tails[threadIdx.x] = 0;
}

__device__ __forceinline__ float edge_e(float2 ns, float2 nd, float Li,
                                        float ci, float Ai, float dt) {
    const float delta = ns.x - nd.x;
    if (delta <= 0.0f) return 0.0f;
    const float x = (delta / Li) * ci;
    const float ec = cbrtf(x) * Ai * dt;
    const float comb = (nd.y * ns.y) / (nd.y + ns.y);
    return fminf(ec, delta * comb);
}

// record = s(17b) | d(17b)<<17 | f16(e)<<34  (only nonzero edges recorded)
__device__ __forceinline__ u64 make_rec(int s, int d, float e) {
    return (u64)(unsigned)s | ((u64)(unsigned)d << 17)
         | ((u64)__half_as_ushort(__float2half_rn(e)) << 34);
}

// One block per 2048-edge window, XCD-swizzled so each slice's records are
// produced and consumed through the SAME XCD's L2. Ballot compaction into
// per-wave LDS segments (zero per-element atomics), ONE global atomic/block.
// etrec is at the divergent-gather hardware floor (~3.8 cy/request, ~80 us;
// invariant across 3 implementations R9/R10/R12) — do not re-attack.
__global__ void __launch_bounds__(512)
etrec_kernel(const float2* __restrict__ nodes,
             const float* __restrict__ L,
             const float* __restrict__ cond,
             const float* __restrict__ A,
             const float* __restrict__ time_step,
             const int* __restrict__ src,
             const int* __restrict__ dst,
             u64* __restrict__ recs,      // [SLICES][cap]
             int* __restrict__ tails,     // [SLICES]
             int n_edges, int wps, int cap) {
    __shared__ u64 srec[8 * 256];        // 8 waves x 256 records, 16 KB
    __shared__ int wcnt[8];
    __shared__ int wbase[8];
    __shared__ int sbase;

    const int wpx  = SL_XCD * wps;                        // windows per xcd
    const int w    = (blockIdx.x % N_XCD) * wpx + blockIdx.x / N_XCD;
    const int s    = w / wps;                             // slice of this window
    const int e0   = w * WIN_E;
    const int wave = threadIdx.x >> 6;
    const int lane = threadIdx.x & 63;

    int my_off = 0;                                       // wave-local count
    const bool active = (e0 < n_edges);

    if (active) {
        const float dt = time_step[0];
        float ev[4]; int sv[4]; int dv[4];

        if (e0 + WIN_E <= n_edges) {                      // full window: vec4
            const int kk = (e0 >> 2) + threadIdx.x;       // e0 % 4 == 0
            const int4    si = ((const int4*)src)[kk];
            const int4    di = ((const int4*)dst)[kk];
            const vfloat4 Lv = __builtin_nontemporal_load(&((const vfloat4*)L)[kk]);
            const vfloat4 cv = __builtin_nontemporal_load(&((const vfloat4*)cond)[kk]);
            const vfloat4 Av = __builtin_nontemporal_load(&((const vfloat4*)A)[kk]);
            const float2 ns0 = nodes[si.x], ns1 = nodes[si.y], ns2 = nodes[si.z], ns3 = nodes[si.w];
            const float2 nd0 = nodes[di.x], nd1 = nodes[di.y], nd2 = nodes[di.z], nd3 = nodes[di.w];
            ev[0] = edge_e(ns0, nd0, Lv.x, cv.x, Av.x, dt);
            ev[1] = edge_e(ns1, nd1, Lv.y, cv.y, Av.y, dt);
            ev[2] = edge_e(ns2, nd2, Lv.z, cv.z, Av.z, dt);
            ev[3] = edge_e(ns3, nd3, Lv.w, cv.w, Av.w, dt);
            sv[0] = si.x; sv[1] = si.y; sv[2] = si.z; sv[3] = si.w;
            dv[0] = di.x; dv[1] = di.y; dv[2] = di.z; dv[3] = di.w;
        } else {                                          // partial last window
#pragma unroll
            for (int j = 0; j < 4; ++j) {
                const int i = e0 + 4 * (int)threadIdx.x + j;
                float e = 0.0f; int a = 0, b2 = 0;
                if (i < n_edges) {
                    a = src[i]; b2 = dst[i];
                    e = edge_e(nodes[a], nodes[b2], L[i], cond[i], A[i], dt);
                }
                ev[j] = e; sv[j] = a; dv[j] = b2;
            }
        }

#pragma unroll
        for (int j = 0; j < 4; ++j) {
            const u64 mask = __ballot(ev[j] > 0.0f);
            if (ev[j] > 0.0f) {
                const int pos = my_off + __popcll(mask & ((1ull << lane) - 1ull));
                srec[(wave << 8) + pos] = make_rec(sv[j], dv[j], ev[j]);
            }
            my_off += (int)__popcll(mask);
        }
    }

    if (lane == 0) wcnt[wave] = my_off;
    __syncthreads();
    if (threadIdx.x == 0) {
        int tot = 0;
#pragma unroll
        for (int i = 0; i < 8; ++i) { wbase[i] = tot; tot += wcnt[i]; }
        sbase = (tot > 0) ? atomicAdd(&tails[s], tot) : 0;  // ONE atomic/block
    }
    __syncthreads();

    if (active) {
        const int c  = wcnt[wave];
        const int gb = sbase + wbase[wave];
        u64* __restrict__ dp = recs + (size_t)s * cap;
        for (int t = lane; t < c; t += 64) {
            const int p = gb + t;
            if (p < cap) dp[p] = srec[(wave << 8) + t];
        }
    }
}

__device__ __forceinline__ void acc_rec(u64 rec, float* __restrict__ lds,
                                        int base, int rlen) {
    const int   sv = (int)(rec & 0x1FFFF);
    const int   dv = (int)((rec >> 17) & 0x1FFFF);
    const float e  = __half2float(__ushort_as_half((unsigned short)(rec >> 34)));
    const int ls = sv - base; if ((unsigned)ls < (unsigned)rlen) atomicAdd(&lds[ls], -e);
    const int ld = dv - base; if ((unsigned)ld < (unsigned)rlen) atomicAdd(&lds[ld],  e);
}

// Block (r,b) XCD-swizzled; scans slice b's compacted records (8B/nonzero
// edge, XCD-L2-resident across the 8 range re-reads). Scan: 2 independent
// 16B loads (4 records) per step — MLP, since grid caps us at 2 blocks/CU.
__global__ void __launch_bounds__(512)
accrec_kernel(const u64* __restrict__ recs,
              const int* __restrict__ tails,
              float* __restrict__ copies,   // [SLICES][n_nodes]
              int n_nodes, int R, int cap) {
    __shared__ float lds[RLEN_MAX];
    const int xcd = blockIdx.x % N_XCD;
    const int j   = blockIdx.x / N_XCD;
    const int r   = j % NRANGE;
    const int b   = xcd * SL_XCD + j / NRANGE;
    const int base = r * R;
    const int rlen = min(R, n_nodes - base);

    for (int t = threadIdx.x; t < rlen; t += 512) lds[t] = 0.0f;
    __syncthreads();

    const int cnt = min(tails[b], cap);
    const u64* __restrict__ g = recs + (size_t)b * cap;   // cap*8B: 16B-aligned
    const int npair = cnt >> 1;
    const ulonglong2* __restrict__ g2 = (const ulonglong2*)g;
    for (int t = threadIdx.x; t < npair; t += 1024) {
        const int t2 = t + 512;
        const bool h2 = (t2 < npair);
        // both loads issued before any use
        const ulonglong2 r0 = g2[t];
        ulonglong2 r1;
        if (h2) r1 = g2[t2];
        acc_rec(r0.x, lds, base, rlen);
        acc_rec(r0.y, lds, base, rlen);
        if (h2) {
            acc_rec(r1.x, lds, base, rlen);
            acc_rec(r1.y, lds, base, rlen);
        }
    }
    // odd tail record
    for (int t = (npair << 1) + (int)threadIdx.x; t < cnt; t += 512)
        acc_rec(g[t], lds, base, rlen);
    __syncthreads();

    // Exclusive region of copies[b]: plain coalesced stores (covers all rlen).
    float* __restrict__ cpy = copies + (size_t)b * n_nodes + base;
    for (int t = threadIdx.x; t < rlen; t += 512) cpy[t] = lds[t];
}

// out[i..i+3] = sum over the slices, float4-vectorized.
__global__ void __launch_bounds__(256)
reduce_copies_kernel(const float* __restrict__ copies, float* __restrict__ out,
                     int n_nodes) {
    const int k = blockIdx.x * blockDim.x + threadIdx.x;
    const int nvec = n_nodes >> 2;
    if (k < nvec) {
        vfloat4 v = {0.f, 0.f, 0.f, 0.f};
        for (int b = 0; b < SLICES; ++b)
            v += ((const vfloat4*)(copies + (size_t)b * n_nodes))[k];
        ((vfloat4*)out)[k] = v;
    } else if (k == nvec) {
        for (int i = nvec << 2; i < n_nodes; ++i) {
            float v = 0.0f;
            for (int b = 0; b < SLICES; ++b) v += copies[(size_t)b * n_nodes + i];
            out[i] = v;
        }
    }
}

// Fallback (shape/ws mismatch): direct device-scope atomics into d_out.
__global__ void __launch_bounds__(256)
conduction_edge_direct(const float* __restrict__ T, const float* __restrict__ cp,
                       const float* __restrict__ L, const float* __restrict__ cond,
                       const float* __restrict__ A, const float* __restrict__ time_step,
                       const int* __restrict__ src, const int* __restrict__ dst,
                       float* __restrict__ out, int n_edges) {
    int i = blockIdx.x * blockDim.x + threadIdx.x;
    if (i >= n_edges) return;
    const int s = src[i], d = dst[i];
    float delta = T[s] - T[d];
    if (delta <= 0.0f) return;
    const float dt = time_step[0];
    const float x = (delta / L[i]) * cond[i];
    const float e_cond = cbrtf(x) * A[i] * dt;
    const float cs = cp[s], cd = cp[d];
    const float max_e = delta * (cd * cs) / (cd + cs);
    const float Et = fminf(e_cond, max_e);
    atomicAdd(&out[d],  Et);
    atomicAdd(&out[s], -Et);
}

extern "C" void kernel_launch(void* const* d_in, const int* in_sizes, int n_in,
                              void* d_out, int out_size, void* d_ws, size_t ws_size,
                              hipStream_t stream) {
    const float* T    = (const float*)d_in[0];
    const float* cp   = (const float*)d_in[1];
    const float* L    = (const float*)d_in[2];
    const float* cond = (const float*)d_in[3];
    const float* A    = (const float*)d_in[4];
    const float* ts   = (const float*)d_in[5];
    const int*   src  = (const int*)d_in[6];
    const int*   dst  = (const int*)d_in[7];
    float* out = (float*)d_out;

    const int n_nodes = in_sizes[0];
    const int n_edges = in_sizes[2];

    const int block = 256;
    const int ngrid = (n_nodes + block - 1) / block;
    const int R = (n_nodes + NRANGE - 1) / NRANGE;

    // chunk (edges/slice): multiple of WIN_E so windows never straddle slices
    int chunk = (n_edges + SLICES - 1) / SLICES;
    chunk = (chunk + WIN_E - 1) & ~(WIN_E - 1);
    const int wps = chunk / WIN_E;                 // windows per slice
    const int cap = (chunk >> 3) * 5;              // 62.5% of chunk (~+80 sigma)

    const size_t tails_bytes = 256;                                // 64*4
    const size_t nodes_bytes = (size_t)n_nodes * sizeof(float2);
    const size_t recs_bytes  = (size_t)SLICES * cap * sizeof(u64);
    const size_t copy_bytes  = (size_t)SLICES * n_nodes * sizeof(float);
    const size_t need = tails_bytes + nodes_bytes + recs_bytes + copy_bytes;

    if (R <= RLEN_MAX && n_nodes <= (1 << 17) && ws_size >= need) {
        int*    tails  = (int*)d_ws;
        float2* nodes  = (float2*)((char*)d_ws + tails_bytes);
        u64*    recs   = (u64*)((char*)d_ws + tails_bytes + nodes_bytes);
        float*  copies = (float*)((char*)d_ws + tails_bytes + nodes_bytes + recs_bytes);

        pack_nodes_kernel<<<ngrid, block, 0, stream>>>(T, cp, nodes, tails, n_nodes);
        etrec_kernel<<<SLICES * wps, 512, 0, stream>>>(
            nodes, L, cond, A, ts, src, dst, recs, tails, n_edges, wps, cap);
        accrec_kernel<<<N_XCD * SL_XCD * NRANGE, 512, 0, stream>>>(
            recs, tails, copies, n_nodes, R, cap);
        const int rgrid = ((n_nodes >> 2) + 1 + block - 1) / block;
        reduce_copies_kernel<<<rgrid, block, 0, stream>>>(copies, out, n_nodes);
    } else {
        (void)hipMemsetAsync(out, 0, (size_t)out_size * sizeof(float), stream);
        const int egrid = (n_edges + block - 1) / block;
        conduction_edge_direct<<<egrid, block, 0, stream>>>(
            T, cp, L, cond, A, ts, src, dst, out, n_edges);
    }
}